// Round 1
// baseline (52.424 us; speedup 1.0000x reference)
//
#include <hip/hip_runtime.h>

typedef unsigned short u16;
typedef __attribute__((ext_vector_type(4))) float f32x4;
typedef __attribute__((ext_vector_type(8))) short short8;

#define D0 784
#define D1 128
#define D2 64
#define D3 10
#define KS0 25
#define KS1 4
#define KS2 2

// workspace byte offsets
#define WS_W0P 0        // 25*128*32 u16 = 204800 B
#define WS_W1P 204800   // 4*64*32 u16   = 16384 B  (W2P contiguous after)
#define WS_W2P 221184   // 2*16*32 u16   = 2048 B
#define WS_B0  223232   // 128 f32
#define WS_B1  223744   // 64 f32
#define WS_B2  224000   // 16 f32

__device__ __forceinline__ u16 f2bf(float f) {
  union { float f; unsigned u; } v; v.f = f;
  unsigned u = v.u;
  return (u16)((u + 0x7fffu + ((u >> 16) & 1u)) >> 16);  // RNE f32->bf16
}

// element offset of (col c, k-in-tile kk) inside a [C][32] bf16 k-step tile,
// with 16B-chunk XOR swizzle so ds_read_b128 of B-fragments is conflict-free.
__device__ __forceinline__ int swz(int c, int kk) {
  return c * 32 + (((kk >> 3) ^ ((c >> 1) & 3)) << 3) + (kk & 7);
}

__global__ void prep_kernel(const float* __restrict__ W0, const float* __restrict__ W1,
                            const float* __restrict__ W2, u16* __restrict__ w0p,
                            u16* __restrict__ w1p, u16* __restrict__ w2p,
                            float* __restrict__ b0, float* __restrict__ b1,
                            float* __restrict__ b2) {
  int idx = blockIdx.x * 256 + threadIdx.x;
  if (idx < 25 * 128 * 32) {  // W0 pack: [785][128] -> [25][128][32] bf16 (k padded)
    int ks = idx / 4096, rem = idx % 4096, c = rem >> 5, kk = rem & 31;
    int k = ks * 32 + kk;
    float v = (k < D0) ? W0[k * D1 + c] : 0.f;
    w0p[ks * 4096 + swz(c, kk)] = f2bf(v);
    return;
  }
  idx -= 25 * 128 * 32;
  if (idx < 4 * 64 * 32) {  // W1 pack: [129][64] -> [4][64][32]
    int ks = idx / 2048, rem = idx % 2048, c = rem >> 5, kk = rem & 31;
    int k = ks * 32 + kk;
    w1p[ks * 2048 + swz(c, kk)] = f2bf(W1[k * D2 + c]);
    return;
  }
  idx -= 4 * 64 * 32;
  if (idx < 2 * 16 * 32) {  // W2 pack: [65][10] -> [2][16][32] (cols padded to 16)
    int ks = idx / 512, rem = idx % 512, c = rem >> 5, kk = rem & 31;
    int k = ks * 32 + kk;
    float v = (c < D3) ? W2[k * D3 + c] : 0.f;
    w2p[ks * 512 + swz(c, kk)] = f2bf(v);
    return;
  }
  idx -= 2 * 16 * 32;
  if (idx < 128) { b0[idx] = W0[D0 * D1 + idx]; return; }
  idx -= 128;
  if (idx < 64) { b1[idx] = W1[D1 * D2 + idx]; return; }
  idx -= 64;
  if (idx < 16) { b2[idx] = (idx < D3) ? W2[D2 * D3 + idx] : 0.f; }
}

__device__ __forceinline__ void gload_lds16(const void* g, void* l) {
  __builtin_amdgcn_global_load_lds((const __attribute__((address_space(1))) void*)g,
                                   (__attribute__((address_space(3))) void*)l, 16, 0, 0);
}

__global__ __launch_bounds__(256) void mlp_fused(
    const float* __restrict__ X, const u16* __restrict__ w0p,
    const u16* __restrict__ w1p, const float* __restrict__ b0,
    const float* __restrict__ b1, const float* __restrict__ b2,
    float* __restrict__ out) {
  __shared__ __attribute__((aligned(16))) u16 smW0[2][4096];      // 2 x 8 KB k-step tiles
  __shared__ __attribute__((aligned(16))) u16 smW12[9216];        // W1p (8192) + W2p (1024)
  __shared__ __attribute__((aligned(16))) u16 smH0[4][16][136];   // per-wave h0, +8 pad
  __shared__ __attribute__((aligned(16))) u16 smH1[4][16][72];    // per-wave h1, +8 pad

  const int t = threadIdx.x;
  const int lane = t & 63;
  const int wv = t >> 6;
  const int q = lane >> 4;    // quarter-wave id: A/B k-group, C row-group
  const int lr = lane & 15;   // A row / B,C col within fragment

  // stage W1p + W2p (contiguous 18432 B in ws) into LDS
  {
    const char* src = (const char*)w1p;
    char* dst = (char*)smW12;
    for (int off = wv * 1024; off < 18432; off += 4096)
      gload_lds16(src + off + lane * 16, dst + off);
  }
  // W0 k-tile staging: each wave copies 2 KB (2 x 1 KB instructions)
  auto stageW0 = [&](int buf, int ks) {
    const char* src = (const char*)(w0p + ks * 4096) + wv * 2048 + lane * 16;
    char* dst = (char*)&smW0[buf][0] + wv * 2048;
    gload_lds16(src, dst);
    gload_lds16(src + 1024, dst + 1024);
  };

  const int row = blockIdx.x * 64 + wv * 16 + lr;
  const float* xrow = X + (size_t)row * D0;

  f32x4 acc0[8];
#pragma unroll
  for (int f = 0; f < 8; ++f) acc0[f] = (f32x4){0.f, 0.f, 0.f, 0.f};

  // prefetch A for ks=0 (always in range: q*8+7 <= 31 < 784)
  f32x4 xa, xb;
  {
    const f32x4* xp = (const f32x4*)(xrow + q * 8);
    xa = xp[0]; xb = xp[1];
  }
  stageW0(0, 0);
  __syncthreads();

  int buf = 0;
  for (int ks = 0; ks < KS0; ++ks) {
    if (ks + 1 < KS0) stageW0(buf ^ 1, ks + 1);
    f32x4 na = (f32x4){0.f, 0.f, 0.f, 0.f}, nb = (f32x4){0.f, 0.f, 0.f, 0.f};
    if (ks + 1 < KS0) {
      int kb = (ks + 1) * 32 + q * 8;
      if (kb < D0) {  // k-tail (>=784) contributes 0 anyway (W0p zero-padded)
        const f32x4* xp = (const f32x4*)(xrow + kb);
        na = xp[0]; nb = xp[1];
      }
    }
    short8 a;
    a[0] = (short)f2bf(xa[0]); a[1] = (short)f2bf(xa[1]);
    a[2] = (short)f2bf(xa[2]); a[3] = (short)f2bf(xa[3]);
    a[4] = (short)f2bf(xb[0]); a[5] = (short)f2bf(xb[1]);
    a[6] = (short)f2bf(xb[2]); a[7] = (short)f2bf(xb[3]);
    const u16* smb = &smW0[buf][0];
#pragma unroll
    for (int f = 0; f < 8; ++f) {
      int c = f * 16 + lr;
      int js = q ^ ((c >> 1) & 3);
      short8 b = *(const short8*)(smb + c * 32 + js * 8);
      acc0[f] = __builtin_amdgcn_mfma_f32_16x16x32_bf16(a, b, acc0[f], 0, 0, 0);
    }
    __syncthreads();
    xa = na; xb = nb; buf ^= 1;
  }

  // layer-0 epilogue: bias + relu -> per-wave LDS h0 (bf16)
#pragma unroll
  for (int f = 0; f < 8; ++f) {
    int c = f * 16 + lr;
    float bb = b0[c];
#pragma unroll
    for (int r = 0; r < 4; ++r) {
      float v = acc0[f][r] + bb;
      smH0[wv][q * 4 + r][c] = f2bf(fmaxf(v, 0.f));
    }
  }

  // layer 1: [16x128] @ [128x64], K-steps from per-wave h0
  f32x4 acc1[4];
#pragma unroll
  for (int f = 0; f < 4; ++f) acc1[f] = (f32x4){0.f, 0.f, 0.f, 0.f};
  const u16* h0row = &smH0[wv][lr][0];
#pragma unroll
  for (int ks = 0; ks < KS1; ++ks) {
    short8 a = *(const short8*)(h0row + ks * 32 + q * 8);
#pragma unroll
    for (int f = 0; f < 4; ++f) {
      int c = f * 16 + lr;
      int js = q ^ ((c >> 1) & 3);
      short8 b = *(const short8*)(smW12 + ks * 2048 + c * 32 + js * 8);
      acc1[f] = __builtin_amdgcn_mfma_f32_16x16x32_bf16(a, b, acc1[f], 0, 0, 0);
    }
  }
#pragma unroll
  for (int f = 0; f < 4; ++f) {
    int c = f * 16 + lr;
    float bb = b1[c];
#pragma unroll
    for (int r = 0; r < 4; ++r)
      smH1[wv][q * 4 + r][c] = f2bf(fmaxf(acc1[f][r] + bb, 0.f));
  }

  // layer 2: [16x64] @ [64x16(10 valid)]
  f32x4 acc2 = (f32x4){0.f, 0.f, 0.f, 0.f};
  const u16* h1row = &smH1[wv][lr][0];
  const u16* w2sm = smW12 + 8192;
#pragma unroll
  for (int ks = 0; ks < KS2; ++ks) {
    short8 a = *(const short8*)(h1row + ks * 32 + q * 8);
    int js = q ^ ((lr >> 1) & 3);
    short8 b = *(const short8*)(w2sm + ks * 512 + lr * 32 + js * 8);
    acc2 = __builtin_amdgcn_mfma_f32_16x16x32_bf16(a, b, acc2, 0, 0, 0);
  }
  if (lr < D3) {
    float bb = b2[lr];
#pragma unroll
    for (int r = 0; r < 4; ++r) {
      int rowg = blockIdx.x * 64 + wv * 16 + q * 4 + r;
      out[rowg * D3 + lr] = acc2[r] + bb;
    }
  }
}

extern "C" void kernel_launch(void* const* d_in, const int* in_sizes, int n_in,
                              void* d_out, int out_size, void* d_ws, size_t ws_size,
                              hipStream_t stream) {
  const float* X  = (const float*)d_in[0];
  const float* W0 = (const float*)d_in[1];
  const float* W1 = (const float*)d_in[2];
  const float* W2 = (const float*)d_in[3];
  float* out = (float*)d_out;
  char* ws = (char*)d_ws;
  u16* w0p = (u16*)(ws + WS_W0P);
  u16* w1p = (u16*)(ws + WS_W1P);
  u16* w2p = (u16*)(ws + WS_W2P);
  float* b0 = (float*)(ws + WS_B0);
  float* b1 = (float*)(ws + WS_B1);
  float* b2 = (float*)(ws + WS_B2);

  // total prep elements: 102400 + 8192 + 1024 + 128 + 64 + 16 = 111824
  prep_kernel<<<437, 256, 0, stream>>>(W0, W1, W2, w0p, w1p, w2p, b0, b1, b2);
  mlp_fused<<<65536 / 64, 256, 0, stream>>>(X, w0p, w1p, b0, b1, b2, out);
}

// Round 2
// 45.223 us; speedup vs baseline: 1.1592x; 1.1592x over previous
//
#include <hip/hip_runtime.h>

typedef unsigned short u16;
typedef __attribute__((ext_vector_type(4))) float f32x4;
typedef __attribute__((ext_vector_type(8))) short short8;

#define D0 784
#define D1 128
#define D2 64
#define D3 10
#define KS0 25
#define KS1 4
#define KS2 2

// workspace byte offsets
#define WS_W0P 0        // 25*128*32 u16 = 204800 B
#define WS_W1P 204800   // 4*64*32 u16   = 16384 B  (W2P contiguous after)
#define WS_W2P 221184   // 2*16*32 u16   = 2048 B
#define WS_B0  223232   // 128 f32
#define WS_B1  223744   // 64 f32
#define WS_B2  224000   // 16 f32

__device__ __forceinline__ u16 f2bf(float f) {
  union { float f; unsigned u; } v; v.f = f;
  unsigned u = v.u;
  return (u16)((u + 0x7fffu + ((u >> 16) & 1u)) >> 16);  // RNE f32->bf16
}

// element offset of (col c, k-in-tile kk) inside a [C][32] bf16 k-step tile,
// with 16B-chunk XOR swizzle so ds_read_b128 of B-fragments is conflict-free.
__device__ __forceinline__ int swz(int c, int kk) {
  return c * 32 + (((kk >> 3) ^ ((c >> 1) & 3)) << 3) + (kk & 7);
}

__global__ void prep_kernel(const float* __restrict__ W0, const float* __restrict__ W1,
                            const float* __restrict__ W2, u16* __restrict__ w0p,
                            u16* __restrict__ w1p, u16* __restrict__ w2p,
                            float* __restrict__ b0, float* __restrict__ b1,
                            float* __restrict__ b2) {
  int idx = blockIdx.x * 256 + threadIdx.x;
  if (idx < 25 * 128 * 32) {  // W0 pack: [785][128] -> [25][128][32] bf16 (k padded)
    int ks = idx / 4096, rem = idx % 4096, c = rem >> 5, kk = rem & 31;
    int k = ks * 32 + kk;
    float v = (k < D0) ? W0[k * D1 + c] : 0.f;
    w0p[ks * 4096 + swz(c, kk)] = f2bf(v);
    return;
  }
  idx -= 25 * 128 * 32;
  if (idx < 4 * 64 * 32) {  // W1 pack: [129][64] -> [4][64][32]
    int ks = idx / 2048, rem = idx % 2048, c = rem >> 5, kk = rem & 31;
    int k = ks * 32 + kk;
    w1p[ks * 2048 + swz(c, kk)] = f2bf(W1[k * D2 + c]);
    return;
  }
  idx -= 4 * 64 * 32;
  if (idx < 2 * 16 * 32) {  // W2 pack: [65][10] -> [2][16][32] (cols padded to 16)
    int ks = idx / 512, rem = idx % 512, c = rem >> 5, kk = rem & 31;
    int k = ks * 32 + kk;
    float v = (c < D3) ? W2[k * D3 + c] : 0.f;
    w2p[ks * 512 + swz(c, kk)] = f2bf(v);
    return;
  }
  idx -= 2 * 16 * 32;
  if (idx < 128) { b0[idx] = W0[D0 * D1 + idx]; return; }
  idx -= 128;
  if (idx < 64) { b1[idx] = W1[D1 * D2 + idx]; return; }
  idx -= 64;
  if (idx < 16) { b2[idx] = (idx < D3) ? W2[D2 * D3 + idx] : 0.f; }
}

__device__ __forceinline__ void gload_lds16(const void* g, void* l) {
  __builtin_amdgcn_global_load_lds((const __attribute__((address_space(1))) void*)g,
                                   (__attribute__((address_space(3))) void*)l, 16, 0, 0);
}

__device__ __forceinline__ void cvtpk(unsigned& d, float lo, float hi) {
  asm("v_cvt_pk_bf16_f32 %0, %1, %2" : "=v"(d) : "v"(lo), "v"(hi));
}

__global__ __launch_bounds__(256, 4) void mlp_fused(
    const float* __restrict__ X, const u16* __restrict__ w0p,
    const u16* __restrict__ w1p, const float* __restrict__ b0,
    const float* __restrict__ b1, const float* __restrict__ b2,
    float* __restrict__ out) {
  // smW0 double-buffer (16 KB); after the k-loop it is reused (per-wave 4 KB
  // regions) for h0 (4 KB, XOR-swizzled) then h1 (2 KB, overlays dead h0).
  __shared__ __attribute__((aligned(16))) u16 smW0[2][4096];
  __shared__ __attribute__((aligned(16))) u16 smW12[9216];  // W1p (16 KB) + W2p (2 KB)

  const int t = threadIdx.x;
  const int lane = t & 63;
  const int wv = t >> 6;
  const int q = lane >> 4;    // quarter-wave id: A/B k-group, C row-group
  const int lr = lane & 15;   // A row / B,C col within fragment

  // stage W1p + W2p (contiguous 18432 B in ws) into LDS
  {
    const char* src = (const char*)w1p;
    char* dst = (char*)smW12;
    for (int off = wv * 1024; off < 18432; off += 4096)
      gload_lds16(src + off + lane * 16, dst + off);
  }
  // W0 k-tile staging: each wave copies 2 KB (2 x 1 KB instructions)
  auto stageW0 = [&](int buf, int ks) {
    const char* src = (const char*)(w0p + ks * 4096) + wv * 2048 + lane * 16;
    char* dst = (char*)&smW0[buf][0] + wv * 2048;
    gload_lds16(src, dst);
    gload_lds16(src + 1024, dst + 1024);
  };

  const int row = blockIdx.x * 64 + wv * 16 + lr;
  const float* xrow = X + (size_t)row * D0;

  f32x4 acc0[8];
#pragma unroll
  for (int f = 0; f < 8; ++f) acc0[f] = (f32x4){0.f, 0.f, 0.f, 0.f};

  // prefetch A for ks=0 (always in range: q*8+7 <= 31 < 784)
  f32x4 xa, xb;
  {
    const f32x4* xp = (const f32x4*)(xrow + q * 8);
    xa = xp[0]; xb = xp[1];
  }
  stageW0(0, 0);
  __syncthreads();

  // per-lane constant part of the B-fragment LDS offset (elements)
  const int boff = lr * 32 + (q ^ ((lr >> 1) & 3)) * 8;

  int buf = 0;
  for (int ks = 0; ks < KS0; ++ks) {
    if (ks + 1 < KS0) stageW0(buf ^ 1, ks + 1);
    f32x4 na = (f32x4){0.f, 0.f, 0.f, 0.f}, nb = (f32x4){0.f, 0.f, 0.f, 0.f};
    if (ks + 1 < KS0) {
      int kb = (ks + 1) * 32 + q * 8;
      if (kb < D0) {  // k-tail (>=784) contributes 0 anyway (W0p zero-padded)
        const f32x4* xp = (const f32x4*)(xrow + kb);
        na = xp[0]; nb = xp[1];
      }
    }
    union { short8 s; unsigned u[4]; } a;
    cvtpk(a.u[0], xa[0], xa[1]);
    cvtpk(a.u[1], xa[2], xa[3]);
    cvtpk(a.u[2], xb[0], xb[1]);
    cvtpk(a.u[3], xb[2], xb[3]);
    const u16* smb = &smW0[buf][0];
#pragma unroll
    for (int f = 0; f < 8; ++f) {
      short8 b = *(const short8*)(smb + f * 512 + boff);
      acc0[f] = __builtin_amdgcn_mfma_f32_16x16x32_bf16(a.s, b, acc0[f], 0, 0, 0);
    }
    __syncthreads();
    xa = na; xb = nb; buf ^= 1;
  }

  // ---- per-wave scratch region (overlays smW0, safe after final barrier) ----
  char* hbase = (char*)&smW0[0][0] + wv * 4096;

  // layer-0 epilogue: bias + relu -> swizzled h0[16][128] bf16 (4 KB/wave)
  // byte(r,c) = r*256 + ((c>>3 ^ (r&7))<<4) + (c&7)*2
#pragma unroll
  for (int f = 0; f < 8; ++f) {
    int c = f * 16 + lr;
    float bb = b0[c];
    int chb = ((c >> 3) << 4);
    int cwb = (c & 7) << 1;
#pragma unroll
    for (int r = 0; r < 4; ++r) {
      int rr = q * 4 + r;
      float v = acc0[f][r] + bb;
      *(u16*)(hbase + rr * 256 + (chb ^ ((rr & 7) << 4)) + cwb) = f2bf(fmaxf(v, 0.f));
    }
  }
  __builtin_amdgcn_wave_barrier();  // per-wave data; no cross-wave sync needed

  // layer 1: [16x128] @ [128x64], A-frags from swizzled h0
  f32x4 acc1[4];
#pragma unroll
  for (int f = 0; f < 4; ++f) acc1[f] = (f32x4){0.f, 0.f, 0.f, 0.f};
#pragma unroll
  for (int ks = 0; ks < KS1; ++ks) {
    short8 a = *(const short8*)(hbase + lr * 256 + (((ks * 4 + q) ^ (lr & 7)) << 4));
#pragma unroll
    for (int f = 0; f < 4; ++f) {
      int c = f * 16 + lr;
      int js = q ^ ((c >> 1) & 3);
      short8 b = *(const short8*)(smW12 + ks * 2048 + c * 32 + js * 8);
      acc1[f] = __builtin_amdgcn_mfma_f32_16x16x32_bf16(a, b, acc1[f], 0, 0, 0);
    }
  }
  // layer-1 epilogue -> swizzled h1[16][64] bf16 (2 KB/wave, overlays dead h0)
  // byte(r,c) = r*128 + ((c>>3 ^ (r&7))<<4) + (c&7)*2
#pragma unroll
  for (int f = 0; f < 4; ++f) {
    int c = f * 16 + lr;
    float bb = b1[c];
    int chb = ((c >> 3) << 4);
    int cwb = (c & 7) << 1;
#pragma unroll
    for (int r = 0; r < 4; ++r) {
      int rr = q * 4 + r;
      *(u16*)(hbase + rr * 128 + (chb ^ ((rr & 7) << 4)) + cwb) =
          f2bf(fmaxf(acc1[f][r] + bb, 0.f));
    }
  }
  __builtin_amdgcn_wave_barrier();

  // layer 2: [16x64] @ [64x16(10 valid)]
  f32x4 acc2 = (f32x4){0.f, 0.f, 0.f, 0.f};
  const u16* w2sm = smW12 + 8192;
#pragma unroll
  for (int ks = 0; ks < KS2; ++ks) {
    short8 a = *(const short8*)(hbase + lr * 128 + (((ks * 4 + q) ^ (lr & 7)) << 4));
    int js = q ^ ((lr >> 1) & 3);
    short8 b = *(const short8*)(w2sm + ks * 512 + lr * 32 + js * 8);
    acc2 = __builtin_amdgcn_mfma_f32_16x16x32_bf16(a, b, acc2, 0, 0, 0);
  }
  if (lr < D3) {
    float bb = b2[lr];
#pragma unroll
    for (int r = 0; r < 4; ++r) {
      int rowg = blockIdx.x * 64 + wv * 16 + q * 4 + r;
      out[rowg * D3 + lr] = acc2[r] + bb;
    }
  }
}

extern "C" void kernel_launch(void* const* d_in, const int* in_sizes, int n_in,
                              void* d_out, int out_size, void* d_ws, size_t ws_size,
                              hipStream_t stream) {
  const float* X  = (const float*)d_in[0];
  const float* W0 = (const float*)d_in[1];
  const float* W1 = (const float*)d_in[2];
  const float* W2 = (const float*)d_in[3];
  float* out = (float*)d_out;
  char* ws = (char*)d_ws;
  u16* w0p = (u16*)(ws + WS_W0P);
  u16* w1p = (u16*)(ws + WS_W1P);
  u16* w2p = (u16*)(ws + WS_W2P);
  float* b0 = (float*)(ws + WS_B0);
  float* b1 = (float*)(ws + WS_B1);
  float* b2 = (float*)(ws + WS_B2);

  // total prep elements: 102400 + 8192 + 1024 + 128 + 64 + 16 = 111824
  prep_kernel<<<437, 256, 0, stream>>>(W0, W1, W2, w0p, w1p, w2p, b0, b1, b2);
  mlp_fused<<<65536 / 64, 256, 0, stream>>>(X, w0p, w1p, b0, b1, b2, out);
}